// Round 12
// baseline (147.245 us; speedup 1.0000x reference)
//
#include <hip/hip_runtime.h>
#include <hip/hip_cooperative_groups.h>
#include <stdint.h>

namespace cg = cooperative_groups;

#define NPIX   (16 * 512 * 512)   // 4,194,304
#define IMG    (512 * 512)
#define NB     16

#define CORE   64
#define HALO   8
#define KIT    8      // iterations per round; 200 = 25 * 8
#define NROUND 25
#define TW     88     // fallback tile row stride (words)
#define TH     82
#define TX0    4

#define BM_WORDS  (NPIX / 32)     // 131072 words = 512 KB per bitmap replica
#define NREP      16
#define SAT       256u            // isoCnt >= SAT  =>  n_unique >= 256 => penalty == 16 exactly
#define MAX3(a, b, c) max(max((a), (b)), (c))

// ---------- global max of predict (float4, 16 px/thread) ----------
__global__ __launch_bounds__(256) void k_max(const float4* __restrict__ p, unsigned int* umax) {
    unsigned int m = 0;
    int base = blockIdx.x * 1024;
#pragma unroll
    for (int k = 0; k < 4; ++k) {
        float4 v = p[base + k * 256 + threadIdx.x];
        m = max(m, __float_as_uint(v.x));
        m = max(m, __float_as_uint(v.y));
        m = max(m, __float_as_uint(v.z));
        m = max(m, __float_as_uint(v.w));
    }
    for (int o = 32; o > 0; o >>= 1)
        m = max(m, (unsigned int)__shfl_down(m, o, 64));
    __shared__ unsigned int sm[4];
    int lane = threadIdx.x & 63, w = threadIdx.x >> 6;
    if (lane == 0) sm[w] = m;
    __syncthreads();
    if (threadIdx.x == 0)
        atomicMax(umax, max(max(sm[0], sm[1]), max(sm[2], sm[3])));
}

// ---------- count isolated masked pixels straight from predict ----------
// mask(p) = p > thr. A masked pixel with no masked 8-neighbor keeps its unique
// init id through ALL propagation iterations (values flow only via masked chains),
// so n_unique >= isoCnt; isoCnt >= 256 saturates the penalty clamp at exactly B.
// (px==0 excluded: its id 0 collides with the background key 0.)
__global__ __launch_bounds__(256) void k_iso(const float* __restrict__ pr,
                                             const unsigned int* __restrict__ umax,
                                             unsigned int* __restrict__ isoCnt) {
    const float thr = __uint_as_float(*umax) * 0.5f;
    unsigned int cnt = 0;
    const int tid = threadIdx.x;
    for (int k = 0; k < 8; ++k) {                    // 512 blocks x 8 chunks x 256 thr x 4 px
        int i4 = (blockIdx.x * 8 + k) * 256 + tid;
        int px = i4 * 4;
        int y   = (px >> 9) & 511;                   // row within image (512 rows/image)
        int gxr = px & 511;                          // col of first element
        float4 c = *(const float4*)(pr + px);
        bool m0 = c.x > thr, m1 = c.y > thr, m2 = c.z > thr, m3 = c.w > thr;
        bool lc = (gxr > 0)   && pr[px - 1] > thr;
        bool rc = (gxr < 508) && pr[px + 4] > thr;
        bool u0 = false, u1 = false, u2 = false, u3 = false, lu = false, ru = false;
        if (y > 0) {
            float4 u = *(const float4*)(pr + px - 512);
            u0 = u.x > thr; u1 = u.y > thr; u2 = u.z > thr; u3 = u.w > thr;
            lu = (gxr > 0)   && pr[px - 513] > thr;
            ru = (gxr < 508) && pr[px - 508] > thr;
        }
        bool d0 = false, d1 = false, d2 = false, d3 = false, ld = false, rd = false;
        if (y < 511) {
            float4 d = *(const float4*)(pr + px + 512);
            d0 = d.x > thr; d1 = d.y > thr; d2 = d.z > thr; d3 = d.w > thr;
            ld = (gxr > 0)   && pr[px + 511] > thr;
            rd = (gxr < 508) && pr[px + 516] > thr;
        }
        bool v0 = u0 | d0, v1 = u1 | d1, v2 = u2 | d2, v3 = u3 | d3;
        bool cmL = lu | lc | ld, cmR = ru | rc | rd;
        bool cm0 = v0 | m0, cm1 = v1 | m1, cm2 = v2 | m2, cm3 = v3 | m3;
        cnt += (m0 && !(cmL | cm1 | v0) && px > 0) ? 1u : 0u;
        cnt += (m1 && !(cm0 | cm2 | v1)) ? 1u : 0u;
        cnt += (m2 && !(cm1 | cm3 | v2)) ? 1u : 0u;
        cnt += (m3 && !(cm2 | cmR | v3)) ? 1u : 0u;
    }
    for (int o = 32; o > 0; o >>= 1)
        cnt += __shfl_down(cnt, o, 64);
    __shared__ unsigned int sc[4];
    int lane = tid & 63, w = tid >> 6;
    if (lane == 0) sc[w] = cnt;
    __syncthreads();
    if (tid == 0)
        atomicAdd(isoCnt, sc[0] + sc[1] + sc[2] + sc[3]);
}

// ---------- dice partials always; labels only when fallback will run ----------
__global__ __launch_bounds__(256) void k_init(const float4* __restrict__ pr4,
                                              const float4* __restrict__ tg4,
                                              const unsigned int* __restrict__ umax,
                                              const unsigned int* __restrict__ isoCnt,
                                              int4* __restrict__ lab4,
                                              float* __restrict__ num, float* __restrict__ den) {
    const float thr = __uint_as_float(*umax) * 0.5f;
    const bool wlab = (*isoCnt < SAT);
    float sn = 0.f, sd = 0.f;
    int base = blockIdx.x * 1024;
#pragma unroll
    for (int k = 0; k < 4; ++k) {
        int i4 = base + k * 256 + threadIdx.x;
        float4 p = pr4[i4], t = tg4[i4];
        if (wlab) {
            int pix = i4 * 4;
            int4 L;
            L.x = (p.x > thr) ? pix     : -1;
            L.y = (p.y > thr) ? pix + 1 : -1;
            L.z = (p.z > thr) ? pix + 2 : -1;
            L.w = (p.w > thr) ? pix + 3 : -1;
            lab4[i4] = L;
        }
        sn += p.x * t.x + p.y * t.y + p.z * t.z + p.w * t.w;
        sd += p.x * p.x + p.y * p.y + p.z * p.z + p.w * p.w
            + t.x * t.x + t.y * t.y + t.z * t.z + t.w * t.w;
    }
    for (int o = 32; o > 0; o >>= 1) {
        sn += __shfl_down(sn, o, 64);
        sd += __shfl_down(sd, o, 64);
    }
    __shared__ float wn[4], wd[4];
    int lane = threadIdx.x & 63, w = threadIdx.x >> 6;
    if (lane == 0) { wn[w] = sn; wd[w] = sd; }
    __syncthreads();
    if (threadIdx.x == 0) {
        int b = blockIdx.x >> 6;
        atomicAdd(&num[b * 32], wn[0] + wn[1] + wn[2] + wn[3]);
        atomicAdd(&den[b * 32], wd[0] + wd[1] + wd[2] + wd[3]);
    }
}

// ---------- FALLBACK: cooperative all-200-iteration propagation (gated) ----------
// Also zeroes the bitmap replicas (so no unconditional 8 MB memset in the fast path).
__global__ __launch_bounds__(256, 4) void k_prop_all(int* __restrict__ bufA,
                                                     int* __restrict__ bufB,
                                                     unsigned int* __restrict__ bm,
                                                     const unsigned int* __restrict__ isoCnt) {
    if (*isoCnt >= SAT) return;
    cg::grid_group grid = cg::this_grid();
    __shared__ int T[TH * TW];
    const int tid  = threadIdx.x;
    const int blk  = blockIdx.x;
    const int bx   = blk & 7, by = (blk >> 3) & 7, bimg = blk >> 6;
    const int gx0  = bx * CORE - HALO;
    const int gy0  = by * CORE - HALO;
    int* const base0 = bufA + bimg * IMG;
    int* const base1 = bufB + bimg * IMG;

    // zero bitmap replicas (16 * 512 KB); k_bits runs after this kernel
    {
        int4* bmz = (int4*)bm;
        for (int u = blk * 256 + tid; u < NREP * BM_WORDS / 4; u += 1024 * 256)
            bmz[u] = make_int4(0, 0, 0, 0);
    }

    if (tid < TW) { T[tid] = -1; T[81 * TW + tid] = -1; }
    if (tid < 80) { T[(tid + 1) * TW + 3] = -1; T[(tid + 1) * TW + 84] = -1; }
    for (int u = tid; u < 1600; u += 256) {
        int r = u / 20, c = (u % 20) * 4;
        int gy = gy0 + r, gx = gx0 + c;
        int4 v = (gy >= 0 && gy < 512 && gx >= 0 && gx < 512)
                 ? *(const int4*)(base0 + (gy << 9) + gx)
                 : make_int4(-1, -1, -1, -1);
        *(int4*)&T[(r + 1) * TW + TX0 + c] = v;
    }
    __syncthreads();
    grid.sync();

    const bool active = (tid < 200);
    const int cu = tid % 20, ru = tid / 20;
    const int x0 = cu * 4;
    const int yr = ru * 8;
    int4 O[8];

#define LOAD_ROW(y, V, VL, VR) do {                            \
        const int* _r = &T[((y) + 1) * TW + TX0 + x0];         \
        V  = *(const int4*)_r;                                 \
        VL = _r[-1];                                           \
        VR = _r[4];                                            \
    } while (0)

    for (int r = 0; r < NROUND; ++r) {
        for (int it = 0; it < KIT; ++it) {
            if (active) {
                int4 A, B, C; int Al, Ar, Bl, Br, Cl, Cr;
                LOAD_ROW(yr - 1, A, Al, Ar);
                LOAD_ROW(yr,     B, Bl, Br);
#pragma unroll
                for (int j = 0; j < 8; ++j) {
                    LOAD_ROW(yr + j + 1, C, Cl, Cr);
                    int4 col;
                    col.x = MAX3(A.x, B.x, C.x);
                    col.y = MAX3(A.y, B.y, C.y);
                    col.z = MAX3(A.z, B.z, C.z);
                    col.w = MAX3(A.w, B.w, C.w);
                    int cl = MAX3(Al, Bl, Cl);
                    int cr = MAX3(Ar, Br, Cr);
                    O[j].x = MAX3(cl,    col.x, col.y) | (B.x >> 31);
                    O[j].y = MAX3(col.x, col.y, col.z) | (B.y >> 31);
                    O[j].z = MAX3(col.y, col.z, col.w) | (B.z >> 31);
                    O[j].w = MAX3(col.z, col.w, cr)    | (B.w >> 31);
                    A = B; Al = Bl; Ar = Br;
                    B = C; Bl = Cl; Br = Cr;
                }
            }
            __syncthreads();
            if (active) {
#pragma unroll
                for (int j = 0; j < 8; ++j)
                    *(int4*)&T[(yr + j + 1) * TW + TX0 + x0] = O[j];
            }
            __syncthreads();
        }

        if (r < NROUND - 1) {
            int* dst = (r & 1) ? base1 : base0;
            for (int u = tid; u < 448; u += 256) {
                int lr, lc;
                if (u < 128)      { lr = u >> 4;                lc = u & 15; }
                else if (u < 256) { lr = 56 + ((u - 128) >> 4); lc = u & 15; }
                else { int v = u - 256; lr = 8 + (v >> 2); int s = v & 3; lc = (s < 2) ? s : 12 + s; }
                int4 val = *(const int4*)&T[(HALO + lr + 1) * TW + TX0 + HALO + lc * 4];
                *(int4*)(dst + ((by * CORE + lr) << 9) + bx * CORE + lc * 4) = val;
            }
            __threadfence();
            grid.sync();
            const int* src = (r & 1) ? base1 : base0;
            for (int u = tid; u < 576; u += 256) {
                int lrow, lcu;
                if (u < 160)      { lrow = u / 20;              lcu = u % 20; }
                else if (u < 320) { lrow = 72 + (u - 160) / 20; lcu = u % 20; }
                else { int v = u - 320; lrow = 8 + (v >> 2); int s = v & 3; lcu = (s < 2) ? s : 16 + s; }
                int gy = gy0 + lrow, gx = gx0 + lcu * 4;
                int4 val = (gy >= 0 && gy < 512 && gx >= 0 && gx < 512)
                           ? *(const int4*)(src + (gy << 9) + gx)
                           : make_int4(-1, -1, -1, -1);
                *(int4*)&T[(lrow + 1) * TW + TX0 + lcu * 4] = val;
            }
            __syncthreads();
        } else {
            for (int u = tid; u < 1024; u += 256) {
                int lr = u >> 4, lc = u & 15;
                int4 val = *(const int4*)&T[(HALO + lr + 1) * TW + TX0 + HALO + lc * 4];
                *(int4*)(base0 + ((by * CORE + lr) << 9) + bx * CORE + lc * 4) = val;
            }
        }
    }
#undef LOAD_ROW
}

// ---------- presence bitmap (fallback only) ----------
__global__ __launch_bounds__(256) void k_bits(const int* __restrict__ lab,
                                              unsigned int* __restrict__ bm,
                                              const unsigned int* __restrict__ isoCnt) {
    if (*isoCnt >= SAT) return;
    __shared__ unsigned int sk[1024];
    __shared__ int slot[256];
    const int tid = threadIdx.x;
    unsigned int* rep = bm + (blockIdx.x & (NREP - 1)) * BM_WORDS;
    for (int k = 0; k < 4; ++k) {
        if (k) __syncthreads();
        const int i4 = blockIdx.x * 1024 + k * 256 + tid;
        int4 c = ((const int4*)lab)[i4];
        int pw = __shfl_up(c.w, 1, 64);
        unsigned int prevk;
        if ((tid & 63) == 0) {
            if (i4 == 0) prevk = ~0u;
            else { int pv = lab[i4 * 4 - 1]; prevk = (pv < 0) ? 0u : (unsigned int)pv; }
        } else {
            prevk = (pw < 0) ? 0u : (unsigned int)pw;
        }
        unsigned int k0 = (c.x < 0) ? 0u : (unsigned int)c.x;
        unsigned int k1 = (c.y < 0) ? 0u : (unsigned int)c.y;
        unsigned int k2 = (c.z < 0) ? 0u : (unsigned int)c.z;
        unsigned int k3 = (c.w < 0) ? 0u : (unsigned int)c.w;
        bool c0 = (k0 != prevk), c1 = (k1 != k0), c2 = (k2 != k1), c3 = (k3 != k2);
        sk[0 * 256 + tid] = k0;
        sk[1 * 256 + tid] = k1;
        sk[2 * 256 + tid] = k2;
        sk[3 * 256 + tid] = k3;
        if (c0) slot[k0 & 255] = tid * 4 + 0;
        if (c1) slot[k1 & 255] = tid * 4 + 1;
        if (c2) slot[k2 & 255] = tid * 4 + 2;
        if (c3) slot[k3 & 255] = tid * 4 + 3;
        __syncthreads();
#define SKAT(w) sk[((w) & 3) * 256 + ((w) >> 2)]
        if (c0) { int w = slot[k0 & 255]; if (w != tid * 4 + 0 && SKAT(w) == k0) c0 = false; }
        if (c1) { int w = slot[k1 & 255]; if (w != tid * 4 + 1 && SKAT(w) == k1) c1 = false; }
        if (c2) { int w = slot[k2 & 255]; if (w != tid * 4 + 2 && SKAT(w) == k2) c2 = false; }
        if (c3) { int w = slot[k3 & 255]; if (w != tid * 4 + 3 && SKAT(w) == k3) c3 = false; }
#undef SKAT
#define TSET(kk, cc) if (cc) {                                        \
            unsigned int word = rep[(kk) >> 5];                       \
            if (!((word >> ((kk) & 31)) & 1u))                        \
                atomicOr(&rep[(kk) >> 5], 1u << ((kk) & 31));         \
        }
        TSET(k0, c0); TSET(k1, c1); TSET(k2, c2); TSET(k3, c3);
#undef TSET
    }
}

// ---------- popcount reduce over OR of replicas (fallback only) ----------
__global__ void k_popc(const unsigned int* __restrict__ bm, unsigned int* nuniq, int words,
                       const unsigned int* __restrict__ isoCnt) {
    if (*isoCnt >= SAT) return;
    unsigned int c = 0;
    for (int i = blockIdx.x * blockDim.x + threadIdx.x; i < words; i += gridDim.x * blockDim.x) {
        unsigned int w = 0;
#pragma unroll
        for (int r = 0; r < NREP; ++r) w |= bm[r * BM_WORDS + i];
        c += __popc(w);
    }
    for (int o = 32; o > 0; o >>= 1)
        c += __shfl_down(c, o, 64);
    __shared__ unsigned int sc[4];
    int lane = threadIdx.x & 63, w = threadIdx.x >> 6;
    if (lane == 0) sc[w] = c;
    __syncthreads();
    if (threadIdx.x == 0)
        atomicAdd(nuniq, sc[0] + sc[1] + sc[2] + sc[3]);
}

// ---------- epilogue ----------
__global__ void k_final(const unsigned int* __restrict__ nuniq,
                        const unsigned int* __restrict__ isoCnt,
                        const float* __restrict__ num, const float* __restrict__ den,
                        float* __restrict__ out) {
    float loss = 0.0f;
    for (int b = 0; b < NB; ++b)
        loss += 1.0f - (num[b * 32] + 1.0f) / (den[b * 32] + 1.0f);
    loss *= (1.0f / NB);
    float penalty;
    if (*isoCnt >= SAT) {
        penalty = (float)NB;                    // n_unique >= isoCnt >= 256 => clamp == B exactly
    } else {
        penalty = (float)(*nuniq) / (float)NB;
        if (penalty < 1.0f) penalty = (float)NB;
        penalty = fminf(penalty, (float)NB);
    }
    out[0] = loss * penalty;
}

extern "C" void kernel_launch(void* const* d_in, const int* in_sizes, int n_in,
                              void* d_out, int out_size, void* d_ws, size_t ws_size,
                              hipStream_t stream) {
    const float* predict = (const float*)d_in[0];
    const float* target  = (const float*)d_in[1];
    float* out = (float*)d_out;

    // layout: +0 umax | +4 nuniq | +8 isoCnt | +256 num[512] | +2304 den[512]
    //         +16384 labA (16MB) | labB (16MB) | bm (8MB, disjoint; zeroed by fallback)
    char* ws = (char*)d_ws;
    unsigned int* umax   = (unsigned int*)ws;
    unsigned int* nuniq  = (unsigned int*)(ws + 4);
    unsigned int* isoCnt = (unsigned int*)(ws + 8);
    float* num = (float*)(ws + 256);
    float* den = (float*)(ws + 2304);
    int* labA = (int*)(ws + 16384);
    int* labB = labA + NPIX;
    unsigned int* bm = (unsigned int*)(ws + 16384 + (size_t)2 * NPIX * sizeof(int));

    hipMemsetAsync(ws, 0, 16384, stream);

    k_max<<<1024, 256, 0, stream>>>((const float4*)predict, umax);
    k_iso<<<512, 256, 0, stream>>>(predict, umax, isoCnt);
    k_init<<<1024, 256, 0, stream>>>((const float4*)predict, (const float4*)target,
                                     umax, isoCnt, (int4*)labA, num, den);

    // fallback propagation (no-op when saturated); zeroes bm; labels land in labA
    void* args[] = { (void*)&labA, (void*)&labB, (void*)&bm, (void*)&isoCnt };
    hipLaunchCooperativeKernel((void*)k_prop_all, dim3(1024), dim3(256), args, 0, stream);

    k_bits<<<NPIX / 4096, 256, 0, stream>>>(labA, bm, isoCnt);
    k_popc<<<512, 256, 0, stream>>>(bm, nuniq, BM_WORDS, isoCnt);
    k_final<<<1, 1, 0, stream>>>(nuniq, isoCnt, num, den, out);
}

// Round 13
// 141.184 us; speedup vs baseline: 1.0429x; 1.0429x over previous
//
#include <hip/hip_runtime.h>
#include <hip/hip_cooperative_groups.h>
#include <stdint.h>

namespace cg = cooperative_groups;

#define NPIX   (16 * 512 * 512)   // 4,194,304
#define IMG    (512 * 512)
#define NB     16

#define CORE   64
#define HALO   8
#define KIT    8      // iterations per round; 200 = 25 * 8
#define NROUND 25
#define TW     88     // fallback tile row stride (words)
#define TH     82
#define TX0    4

#define BM_WORDS  (NPIX / 32)     // 131072 words = 512 KB per bitmap replica
#define NREP      16
#define SAT       256u            // isoCnt >= SAT  =>  n_unique >= 256 => penalty == 16 exactly
#define MAX3(a, b, c) max(max((a), (b)), (c))

// ---------- fused: global max of predict + dice partial sums (one 33.6 MB pass) ----------
// Dice partials don't depend on thr, so they ride the max pass.
__global__ __launch_bounds__(256) void k_maxdice(const float4* __restrict__ pr4,
                                                 const float4* __restrict__ tg4,
                                                 unsigned int* __restrict__ umax,
                                                 float* __restrict__ num,
                                                 float* __restrict__ den) {
    unsigned int m = 0;
    float sn = 0.f, sd = 0.f;
    int base = blockIdx.x * 1024;
#pragma unroll
    for (int k = 0; k < 4; ++k) {
        int i4 = base + k * 256 + threadIdx.x;
        float4 p = pr4[i4], t = tg4[i4];
        m = max(m, __float_as_uint(p.x));
        m = max(m, __float_as_uint(p.y));
        m = max(m, __float_as_uint(p.z));
        m = max(m, __float_as_uint(p.w));
        sn += p.x * t.x + p.y * t.y + p.z * t.z + p.w * t.w;
        sd += p.x * p.x + p.y * p.y + p.z * p.z + p.w * p.w
            + t.x * t.x + t.y * t.y + t.z * t.z + t.w * t.w;
    }
    for (int o = 32; o > 0; o >>= 1) {
        m  = max(m, (unsigned int)__shfl_down(m, o, 64));
        sn += __shfl_down(sn, o, 64);
        sd += __shfl_down(sd, o, 64);
    }
    __shared__ unsigned int sm[4];
    __shared__ float wn[4], wd[4];
    int lane = threadIdx.x & 63, w = threadIdx.x >> 6;
    if (lane == 0) { sm[w] = m; wn[w] = sn; wd[w] = sd; }
    __syncthreads();
    if (threadIdx.x == 0) {
        atomicMax(umax, max(max(sm[0], sm[1]), max(sm[2], sm[3])));
        int b = blockIdx.x >> 6;   // 64 blocks per image
        atomicAdd(&num[b * 32], wn[0] + wn[1] + wn[2] + wn[3]);
        atomicAdd(&den[b * 32], wd[0] + wd[1] + wd[2] + wd[3]);
    }
}

// ---------- count isolated masked pixels straight from predict ----------
// mask(p) = p > thr. A masked pixel with no masked 8-neighbor keeps its unique
// init id through ALL propagation iterations (values flow only via masked chains),
// so n_unique >= isoCnt; isoCnt >= 256 saturates the penalty clamp at exactly B.
// (global pixel 0 excluded: its id 0 collides with the background key 0.)
__global__ __launch_bounds__(256) void k_iso(const float* __restrict__ pr,
                                             const unsigned int* __restrict__ umax,
                                             unsigned int* __restrict__ isoCnt) {
    const float thr = __uint_as_float(*umax) * 0.5f;
    unsigned int cnt = 0;
    const int tid = threadIdx.x;
    for (int k = 0; k < 8; ++k) {                    // 512 blocks x 8 chunks x 256 thr x 4 px
        int i4 = (blockIdx.x * 8 + k) * 256 + tid;
        int px = i4 * 4;
        int y   = (px >> 9) & 511;
        int gxr = px & 511;
        float4 c = *(const float4*)(pr + px);
        bool m0 = c.x > thr, m1 = c.y > thr, m2 = c.z > thr, m3 = c.w > thr;
        bool lc = (gxr > 0)   && pr[px - 1] > thr;
        bool rc = (gxr < 508) && pr[px + 4] > thr;
        bool u0 = false, u1 = false, u2 = false, u3 = false, lu = false, ru = false;
        if (y > 0) {
            float4 u = *(const float4*)(pr + px - 512);
            u0 = u.x > thr; u1 = u.y > thr; u2 = u.z > thr; u3 = u.w > thr;
            lu = (gxr > 0)   && pr[px - 513] > thr;
            ru = (gxr < 508) && pr[px - 508] > thr;
        }
        bool d0 = false, d1 = false, d2 = false, d3 = false, ld = false, rd = false;
        if (y < 511) {
            float4 d = *(const float4*)(pr + px + 512);
            d0 = d.x > thr; d1 = d.y > thr; d2 = d.z > thr; d3 = d.w > thr;
            ld = (gxr > 0)   && pr[px + 511] > thr;
            rd = (gxr < 508) && pr[px + 516] > thr;
        }
        bool v0 = u0 | d0, v1 = u1 | d1, v2 = u2 | d2, v3 = u3 | d3;
        bool cmL = lu | lc | ld, cmR = ru | rc | rd;
        bool cm0 = v0 | m0, cm1 = v1 | m1, cm2 = v2 | m2, cm3 = v3 | m3;
        cnt += (m0 && !(cmL | cm1 | v0) && px > 0) ? 1u : 0u;
        cnt += (m1 && !(cm0 | cm2 | v1)) ? 1u : 0u;
        cnt += (m2 && !(cm1 | cm3 | v2)) ? 1u : 0u;
        cnt += (m3 && !(cm2 | cmR | v3)) ? 1u : 0u;
    }
    for (int o = 32; o > 0; o >>= 1)
        cnt += __shfl_down(cnt, o, 64);
    __shared__ unsigned int sc[4];
    int lane = tid & 63, w = tid >> 6;
    if (lane == 0) sc[w] = cnt;
    __syncthreads();
    if (tid == 0)
        atomicAdd(isoCnt, sc[0] + sc[1] + sc[2] + sc[3]);
}

// ---------- FALLBACK: cooperative all-200-iteration propagation (gated) ----------
// Computes init labels from predict directly in its staging phase (no k_init pass);
// also zeroes the bitmap replicas. Only runs when isoCnt < 256.
__global__ __launch_bounds__(256, 4) void k_prop_all(const float* __restrict__ pr,
                                                     int* __restrict__ bufA,
                                                     int* __restrict__ bufB,
                                                     unsigned int* __restrict__ bm,
                                                     const unsigned int* __restrict__ umax,
                                                     const unsigned int* __restrict__ isoCnt) {
    if (*isoCnt >= SAT) return;
    cg::grid_group grid = cg::this_grid();
    __shared__ int T[TH * TW];
    const float thr = __uint_as_float(*umax) * 0.5f;
    const int tid  = threadIdx.x;
    const int blk  = blockIdx.x;
    const int bx   = blk & 7, by = (blk >> 3) & 7, bimg = blk >> 6;
    const int gx0  = bx * CORE - HALO;
    const int gy0  = by * CORE - HALO;
    int* const base0 = bufA + bimg * IMG;
    int* const base1 = bufB + bimg * IMG;
    const float* img = pr + bimg * IMG;

    // zero bitmap replicas (16 * 512 KB); k_bits runs after this kernel
    {
        int4* bmz = (int4*)bm;
        for (int u = blk * 256 + tid; u < NREP * BM_WORDS / 4; u += 1024 * 256)
            bmz[u] = make_int4(0, 0, 0, 0);
    }

    if (tid < TW) { T[tid] = -1; T[81 * TW + tid] = -1; }
    if (tid < 80) { T[(tid + 1) * TW + 3] = -1; T[(tid + 1) * TW + 84] = -1; }
    // stage: labels computed from predict (global pixel ids)
    for (int u = tid; u < 1600; u += 256) {
        int r = u / 20, c = (u % 20) * 4;
        int gy = gy0 + r, gx = gx0 + c;
        int4 v;
        if (gy >= 0 && gy < 512 && gx >= 0 && gx < 512) {
            float4 pv = *(const float4*)(img + (gy << 9) + gx);
            int id = bimg * IMG + (gy << 9) + gx;
            v.x = (pv.x > thr) ? id     : -1;
            v.y = (pv.y > thr) ? id + 1 : -1;
            v.z = (pv.z > thr) ? id + 2 : -1;
            v.w = (pv.w > thr) ? id + 3 : -1;
        } else v = make_int4(-1, -1, -1, -1);
        *(int4*)&T[(r + 1) * TW + TX0 + c] = v;
    }
    __syncthreads();
    grid.sync();

    const bool active = (tid < 200);
    const int cu = tid % 20, ru = tid / 20;
    const int x0 = cu * 4;
    const int yr = ru * 8;
    int4 O[8];

#define LOAD_ROW(y, V, VL, VR) do {                            \
        const int* _r = &T[((y) + 1) * TW + TX0 + x0];         \
        V  = *(const int4*)_r;                                 \
        VL = _r[-1];                                           \
        VR = _r[4];                                            \
    } while (0)

    for (int r = 0; r < NROUND; ++r) {
        for (int it = 0; it < KIT; ++it) {
            if (active) {
                int4 A, B, C; int Al, Ar, Bl, Br, Cl, Cr;
                LOAD_ROW(yr - 1, A, Al, Ar);
                LOAD_ROW(yr,     B, Bl, Br);
#pragma unroll
                for (int j = 0; j < 8; ++j) {
                    LOAD_ROW(yr + j + 1, C, Cl, Cr);
                    int4 col;
                    col.x = MAX3(A.x, B.x, C.x);
                    col.y = MAX3(A.y, B.y, C.y);
                    col.z = MAX3(A.z, B.z, C.z);
                    col.w = MAX3(A.w, B.w, C.w);
                    int cl = MAX3(Al, Bl, Cl);
                    int cr = MAX3(Ar, Br, Cr);
                    O[j].x = MAX3(cl,    col.x, col.y) | (B.x >> 31);
                    O[j].y = MAX3(col.x, col.y, col.z) | (B.y >> 31);
                    O[j].z = MAX3(col.y, col.z, col.w) | (B.z >> 31);
                    O[j].w = MAX3(col.z, col.w, cr)    | (B.w >> 31);
                    A = B; Al = Bl; Ar = Br;
                    B = C; Bl = Cl; Br = Cr;
                }
            }
            __syncthreads();
            if (active) {
#pragma unroll
                for (int j = 0; j < 8; ++j)
                    *(int4*)&T[(yr + j + 1) * TW + TX0 + x0] = O[j];
            }
            __syncthreads();
        }

        if (r < NROUND - 1) {
            int* dst = (r & 1) ? base1 : base0;
            for (int u = tid; u < 448; u += 256) {
                int lr, lc;
                if (u < 128)      { lr = u >> 4;                lc = u & 15; }
                else if (u < 256) { lr = 56 + ((u - 128) >> 4); lc = u & 15; }
                else { int v = u - 256; lr = 8 + (v >> 2); int s = v & 3; lc = (s < 2) ? s : 12 + s; }
                int4 val = *(const int4*)&T[(HALO + lr + 1) * TW + TX0 + HALO + lc * 4];
                *(int4*)(dst + ((by * CORE + lr) << 9) + bx * CORE + lc * 4) = val;
            }
            __threadfence();
            grid.sync();
            const int* src = (r & 1) ? base1 : base0;
            for (int u = tid; u < 576; u += 256) {
                int lrow, lcu;
                if (u < 160)      { lrow = u / 20;              lcu = u % 20; }
                else if (u < 320) { lrow = 72 + (u - 160) / 20; lcu = u % 20; }
                else { int v = u - 320; lrow = 8 + (v >> 2); int s = v & 3; lcu = (s < 2) ? s : 16 + s; }
                int gy = gy0 + lrow, gx = gx0 + lcu * 4;
                int4 val = (gy >= 0 && gy < 512 && gx >= 0 && gx < 512)
                           ? *(const int4*)(src + (gy << 9) + gx)
                           : make_int4(-1, -1, -1, -1);
                *(int4*)&T[(lrow + 1) * TW + TX0 + lcu * 4] = val;
            }
            __syncthreads();
        } else {
            for (int u = tid; u < 1024; u += 256) {
                int lr = u >> 4, lc = u & 15;
                int4 val = *(const int4*)&T[(HALO + lr + 1) * TW + TX0 + HALO + lc * 4];
                *(int4*)(base0 + ((by * CORE + lr) << 9) + bx * CORE + lc * 4) = val;
            }
        }
    }
#undef LOAD_ROW
}

// ---------- presence bitmap (fallback only) ----------
__global__ __launch_bounds__(256) void k_bits(const int* __restrict__ lab,
                                              unsigned int* __restrict__ bm,
                                              const unsigned int* __restrict__ isoCnt) {
    if (*isoCnt >= SAT) return;
    __shared__ unsigned int sk[1024];
    __shared__ int slot[256];
    const int tid = threadIdx.x;
    unsigned int* rep = bm + (blockIdx.x & (NREP - 1)) * BM_WORDS;
    for (int k = 0; k < 4; ++k) {
        if (k) __syncthreads();
        const int i4 = blockIdx.x * 1024 + k * 256 + tid;
        int4 c = ((const int4*)lab)[i4];
        int pw = __shfl_up(c.w, 1, 64);
        unsigned int prevk;
        if ((tid & 63) == 0) {
            if (i4 == 0) prevk = ~0u;
            else { int pv = lab[i4 * 4 - 1]; prevk = (pv < 0) ? 0u : (unsigned int)pv; }
        } else {
            prevk = (pw < 0) ? 0u : (unsigned int)pw;
        }
        unsigned int k0 = (c.x < 0) ? 0u : (unsigned int)c.x;
        unsigned int k1 = (c.y < 0) ? 0u : (unsigned int)c.y;
        unsigned int k2 = (c.z < 0) ? 0u : (unsigned int)c.z;
        unsigned int k3 = (c.w < 0) ? 0u : (unsigned int)c.w;
        bool c0 = (k0 != prevk), c1 = (k1 != k0), c2 = (k2 != k1), c3 = (k3 != k2);
        sk[0 * 256 + tid] = k0;
        sk[1 * 256 + tid] = k1;
        sk[2 * 256 + tid] = k2;
        sk[3 * 256 + tid] = k3;
        if (c0) slot[k0 & 255] = tid * 4 + 0;
        if (c1) slot[k1 & 255] = tid * 4 + 1;
        if (c2) slot[k2 & 255] = tid * 4 + 2;
        if (c3) slot[k3 & 255] = tid * 4 + 3;
        __syncthreads();
#define SKAT(w) sk[((w) & 3) * 256 + ((w) >> 2)]
        if (c0) { int w = slot[k0 & 255]; if (w != tid * 4 + 0 && SKAT(w) == k0) c0 = false; }
        if (c1) { int w = slot[k1 & 255]; if (w != tid * 4 + 1 && SKAT(w) == k1) c1 = false; }
        if (c2) { int w = slot[k2 & 255]; if (w != tid * 4 + 2 && SKAT(w) == k2) c2 = false; }
        if (c3) { int w = slot[k3 & 255]; if (w != tid * 4 + 3 && SKAT(w) == k3) c3 = false; }
#undef SKAT
#define TSET(kk, cc) if (cc) {                                        \
            unsigned int word = rep[(kk) >> 5];                       \
            if (!((word >> ((kk) & 31)) & 1u))                        \
                atomicOr(&rep[(kk) >> 5], 1u << ((kk) & 31));         \
        }
        TSET(k0, c0); TSET(k1, c1); TSET(k2, c2); TSET(k3, c3);
#undef TSET
    }
}

// ---------- popcount reduce over OR of replicas (fallback only) ----------
__global__ void k_popc(const unsigned int* __restrict__ bm, unsigned int* nuniq, int words,
                       const unsigned int* __restrict__ isoCnt) {
    if (*isoCnt >= SAT) return;
    unsigned int c = 0;
    for (int i = blockIdx.x * blockDim.x + threadIdx.x; i < words; i += gridDim.x * blockDim.x) {
        unsigned int w = 0;
#pragma unroll
        for (int r = 0; r < NREP; ++r) w |= bm[r * BM_WORDS + i];
        c += __popc(w);
    }
    for (int o = 32; o > 0; o >>= 1)
        c += __shfl_down(c, o, 64);
    __shared__ unsigned int sc[4];
    int lane = threadIdx.x & 63, w = threadIdx.x >> 6;
    if (lane == 0) sc[w] = c;
    __syncthreads();
    if (threadIdx.x == 0)
        atomicAdd(nuniq, sc[0] + sc[1] + sc[2] + sc[3]);
}

// ---------- epilogue ----------
__global__ void k_final(const unsigned int* __restrict__ nuniq,
                        const unsigned int* __restrict__ isoCnt,
                        const float* __restrict__ num, const float* __restrict__ den,
                        float* __restrict__ out) {
    float loss = 0.0f;
    for (int b = 0; b < NB; ++b)
        loss += 1.0f - (num[b * 32] + 1.0f) / (den[b * 32] + 1.0f);
    loss *= (1.0f / NB);
    float penalty;
    if (*isoCnt >= SAT) {
        penalty = (float)NB;                    // n_unique >= isoCnt >= 256 => clamp == B exactly
    } else {
        penalty = (float)(*nuniq) / (float)NB;
        if (penalty < 1.0f) penalty = (float)NB;
        penalty = fminf(penalty, (float)NB);
    }
    out[0] = loss * penalty;
}

extern "C" void kernel_launch(void* const* d_in, const int* in_sizes, int n_in,
                              void* d_out, int out_size, void* d_ws, size_t ws_size,
                              hipStream_t stream) {
    const float* predict = (const float*)d_in[0];
    const float* target  = (const float*)d_in[1];
    float* out = (float*)d_out;

    // layout: +0 umax | +4 nuniq | +8 isoCnt | +256 num[512] | +2304 den[512]
    //         +16384 labA (16MB) | labB (16MB) | bm (8MB; zeroed by fallback)
    char* ws = (char*)d_ws;
    unsigned int* umax   = (unsigned int*)ws;
    unsigned int* nuniq  = (unsigned int*)(ws + 4);
    unsigned int* isoCnt = (unsigned int*)(ws + 8);
    float* num = (float*)(ws + 256);
    float* den = (float*)(ws + 2304);
    int* labA = (int*)(ws + 16384);
    int* labB = labA + NPIX;
    unsigned int* bm = (unsigned int*)(ws + 16384 + (size_t)2 * NPIX * sizeof(int));

    hipMemsetAsync(ws, 0, 8192, stream);

    k_maxdice<<<1024, 256, 0, stream>>>((const float4*)predict, (const float4*)target,
                                        umax, num, den);
    k_iso<<<512, 256, 0, stream>>>(predict, umax, isoCnt);

    // fallback propagation (no-op when saturated); computes labels from predict,
    // zeroes bm; final labels land in labA
    void* args[] = { (void*)&predict, (void*)&labA, (void*)&labB,
                     (void*)&bm, (void*)&umax, (void*)&isoCnt };
    hipLaunchCooperativeKernel((void*)k_prop_all, dim3(1024), dim3(256), args, 0, stream);

    k_bits<<<NPIX / 4096, 256, 0, stream>>>(labA, bm, isoCnt);
    k_popc<<<512, 256, 0, stream>>>(bm, nuniq, BM_WORDS, isoCnt);
    k_final<<<1, 1, 0, stream>>>(nuniq, isoCnt, num, den, out);
}

// Round 14
// 119.522 us; speedup vs baseline: 1.2320x; 1.1812x over previous
//
#include <hip/hip_runtime.h>
#include <hip/hip_cooperative_groups.h>
#include <stdint.h>

namespace cg = cooperative_groups;

#define NPIX   (16 * 512 * 512)   // 4,194,304
#define IMG    (512 * 512)
#define NB     16

#define CORE   64
#define HALO   8
#define KIT    8      // iterations per round; 200 = 25 * 8
#define NROUND 25
#define TW     88     // fallback tile row stride (words)
#define TH     82
#define TX0    4

#define BM_WORDS  (NPIX / 32)     // 131072 words = 512 KB per bitmap replica
#define NREP      16
#define SAT       256u            // isoSum >= SAT  =>  n_unique >= 256 => penalty == B exactly
#define MAX3(a, b, c) max(max((a), (b)), (c))

// ---------- pass 1: per-block max of predict + dice partials (slotted, no atomics) ----------
// Every slot is written every call (workspace is poisoned between calls).
__global__ __launch_bounds__(256) void k_maxdice(const float4* __restrict__ pr4,
                                                 const float4* __restrict__ tg4,
                                                 unsigned int* __restrict__ umaxArr,
                                                 float* __restrict__ numArr,
                                                 float* __restrict__ denArr) {
    unsigned int m = 0;
    float sn = 0.f, sd = 0.f;
    int base = blockIdx.x * 1024;
#pragma unroll
    for (int k = 0; k < 4; ++k) {
        int i4 = base + k * 256 + threadIdx.x;
        float4 p = pr4[i4], t = tg4[i4];
        m = max(m, __float_as_uint(p.x));
        m = max(m, __float_as_uint(p.y));
        m = max(m, __float_as_uint(p.z));
        m = max(m, __float_as_uint(p.w));
        sn += p.x * t.x + p.y * t.y + p.z * t.z + p.w * t.w;
        sd += p.x * p.x + p.y * p.y + p.z * p.z + p.w * p.w
            + t.x * t.x + t.y * t.y + t.z * t.z + t.w * t.w;
    }
    for (int o = 32; o > 0; o >>= 1) {
        m  = max(m, (unsigned int)__shfl_down(m, o, 64));
        sn += __shfl_down(sn, o, 64);
        sd += __shfl_down(sd, o, 64);
    }
    __shared__ unsigned int sm[4];
    __shared__ float wn[4], wd[4];
    int lane = threadIdx.x & 63, w = threadIdx.x >> 6;
    if (lane == 0) { sm[w] = m; wn[w] = sn; wd[w] = sd; }
    __syncthreads();
    if (threadIdx.x == 0) {
        umaxArr[blockIdx.x] = max(max(sm[0], sm[1]), max(sm[2], sm[3]));
        numArr[blockIdx.x]  = wn[0] + wn[1] + wn[2] + wn[3];
        denArr[blockIdx.x]  = wd[0] + wd[1] + wd[2] + wd[3];
    }
}

// ---------- helper: block-wide max over umaxArr[1024] -> thr ----------
__device__ float block_thr(const unsigned int* __restrict__ umaxArr) {
    const int tid = threadIdx.x;
    unsigned int m = max(max(umaxArr[tid], umaxArr[tid + 256]),
                         max(umaxArr[tid + 512], umaxArr[tid + 768]));
    for (int o = 32; o > 0; o >>= 1)
        m = max(m, (unsigned int)__shfl_down(m, o, 64));
    __shared__ unsigned int sm[4];
    __shared__ unsigned int smax;
    int lane = tid & 63, w = tid >> 6;
    if (lane == 0) sm[w] = m;
    __syncthreads();
    if (tid == 0) smax = max(max(sm[0], sm[1]), max(sm[2], sm[3]));
    __syncthreads();
    return __uint_as_float(smax) * 0.5f;
}

// ---------- helper: block-wide sum over isoArr[512] ----------
__device__ unsigned int block_iso(const unsigned int* __restrict__ isoArr) {
    const int tid = threadIdx.x;
    unsigned int c = isoArr[tid] + isoArr[tid + 256];
    for (int o = 32; o > 0; o >>= 1)
        c += __shfl_down(c, o, 64);
    __shared__ unsigned int sc[4];
    __shared__ unsigned int stot;
    int lane = tid & 63, w = tid >> 6;
    if (lane == 0) sc[w] = c;
    __syncthreads();
    if (tid == 0) stot = sc[0] + sc[1] + sc[2] + sc[3];
    __syncthreads();
    return stot;
}

// ---------- pass 2: count isolated masked pixels straight from predict ----------
// mask(p) = p > thr. A masked pixel with no masked 8-neighbor keeps its unique
// init id through ALL propagation iterations (values flow only via masked chains),
// so n_unique >= isoSum; isoSum >= 256 saturates the penalty clamp at exactly B.
// (global pixel 0 excluded: its id 0 collides with the background key 0.)
__global__ __launch_bounds__(256) void k_iso(const float* __restrict__ pr,
                                             const unsigned int* __restrict__ umaxArr,
                                             unsigned int* __restrict__ isoArr) {
    const float thr = block_thr(umaxArr);
    unsigned int cnt = 0;
    const int tid = threadIdx.x;
    for (int k = 0; k < 8; ++k) {                    // 512 blocks x 8 chunks x 256 thr x 4 px
        int i4 = (blockIdx.x * 8 + k) * 256 + tid;
        int px = i4 * 4;
        int y   = (px >> 9) & 511;
        int gxr = px & 511;
        float4 c = *(const float4*)(pr + px);
        bool m0 = c.x > thr, m1 = c.y > thr, m2 = c.z > thr, m3 = c.w > thr;
        bool lc = (gxr > 0)   && pr[px - 1] > thr;
        bool rc = (gxr < 508) && pr[px + 4] > thr;
        bool u0 = false, u1 = false, u2 = false, u3 = false, lu = false, ru = false;
        if (y > 0) {
            float4 u = *(const float4*)(pr + px - 512);
            u0 = u.x > thr; u1 = u.y > thr; u2 = u.z > thr; u3 = u.w > thr;
            lu = (gxr > 0)   && pr[px - 513] > thr;
            ru = (gxr < 508) && pr[px - 508] > thr;
        }
        bool d0 = false, d1 = false, d2 = false, d3 = false, ld = false, rd = false;
        if (y < 511) {
            float4 d = *(const float4*)(pr + px + 512);
            d0 = d.x > thr; d1 = d.y > thr; d2 = d.z > thr; d3 = d.w > thr;
            ld = (gxr > 0)   && pr[px + 511] > thr;
            rd = (gxr < 508) && pr[px + 516] > thr;
        }
        bool v0 = u0 | d0, v1 = u1 | d1, v2 = u2 | d2, v3 = u3 | d3;
        bool cmL = lu | lc | ld, cmR = ru | rc | rd;
        bool cm0 = v0 | m0, cm1 = v1 | m1, cm2 = v2 | m2, cm3 = v3 | m3;
        cnt += (m0 && !(cmL | cm1 | v0) && px > 0) ? 1u : 0u;
        cnt += (m1 && !(cm0 | cm2 | v1)) ? 1u : 0u;
        cnt += (m2 && !(cm1 | cm3 | v2)) ? 1u : 0u;
        cnt += (m3 && !(cm2 | cmR | v3)) ? 1u : 0u;
    }
    for (int o = 32; o > 0; o >>= 1)
        cnt += __shfl_down(cnt, o, 64);
    __shared__ unsigned int sc[4];
    int lane = tid & 63, w = tid >> 6;
    if (lane == 0) sc[w] = cnt;
    __syncthreads();
    if (tid == 0)
        isoArr[blockIdx.x] = sc[0] + sc[1] + sc[2] + sc[3];
}

// ---------- FALLBACK: cooperative propagation + unique-count (gated; fast path exits) ----------
// Runs only when isoSum < 256. Stages labels from predict, does 200 iterations with
// ring exchange, then bits + popcount phases (bitmap replicas in bm, count into nuniq).
__global__ __launch_bounds__(256, 4) void k_prop_all(const float* __restrict__ pr,
                                                     int* __restrict__ bufA,
                                                     int* __restrict__ bufB,
                                                     unsigned int* __restrict__ bm,
                                                     const unsigned int* __restrict__ umaxArr,
                                                     const unsigned int* __restrict__ isoArr,
                                                     unsigned int* __restrict__ nuniq) {
    if (block_iso(isoArr) >= SAT) return;            // uniform across all blocks
    cg::grid_group grid = cg::this_grid();
    __shared__ int T[TH * TW];
    const float thr = block_thr(umaxArr);
    const int tid  = threadIdx.x;
    const int blk  = blockIdx.x;
    const int bx   = blk & 7, by = (blk >> 3) & 7, bimg = blk >> 6;
    const int gx0  = bx * CORE - HALO;
    const int gy0  = by * CORE - HALO;
    int* const base0 = bufA + bimg * IMG;
    int* const base1 = bufB + bimg * IMG;
    const float* img = pr + bimg * IMG;

    if (blk == 0 && tid == 0) *nuniq = 0;            // consumed only after later grid.syncs
    {   // zero bitmap replicas (16 * 512 KB)
        int4* bmz = (int4*)bm;
        for (int u = blk * 256 + tid; u < NREP * BM_WORDS / 4; u += 1024 * 256)
            bmz[u] = make_int4(0, 0, 0, 0);
    }

    if (tid < TW) { T[tid] = -1; T[81 * TW + tid] = -1; }
    if (tid < 80) { T[(tid + 1) * TW + 3] = -1; T[(tid + 1) * TW + 84] = -1; }
    // stage: labels computed from predict (global pixel ids)
    for (int u = tid; u < 1600; u += 256) {
        int r = u / 20, c = (u % 20) * 4;
        int gy = gy0 + r, gx = gx0 + c;
        int4 v;
        if (gy >= 0 && gy < 512 && gx >= 0 && gx < 512) {
            float4 pv = *(const float4*)(img + (gy << 9) + gx);
            int id = bimg * IMG + (gy << 9) + gx;
            v.x = (pv.x > thr) ? id     : -1;
            v.y = (pv.y > thr) ? id + 1 : -1;
            v.z = (pv.z > thr) ? id + 2 : -1;
            v.w = (pv.w > thr) ? id + 3 : -1;
        } else v = make_int4(-1, -1, -1, -1);
        *(int4*)&T[(r + 1) * TW + TX0 + c] = v;
    }
    __syncthreads();
    grid.sync();

    const bool active = (tid < 200);
    const int cu = tid % 20, ru = tid / 20;
    const int x0 = cu * 4;
    const int yr = ru * 8;
    int4 O[8];

#define LOAD_ROW(y, V, VL, VR) do {                            \
        const int* _r = &T[((y) + 1) * TW + TX0 + x0];         \
        V  = *(const int4*)_r;                                 \
        VL = _r[-1];                                           \
        VR = _r[4];                                            \
    } while (0)

    for (int r = 0; r < NROUND; ++r) {
        for (int it = 0; it < KIT; ++it) {
            if (active) {
                int4 A, B, C; int Al, Ar, Bl, Br, Cl, Cr;
                LOAD_ROW(yr - 1, A, Al, Ar);
                LOAD_ROW(yr,     B, Bl, Br);
#pragma unroll
                for (int j = 0; j < 8; ++j) {
                    LOAD_ROW(yr + j + 1, C, Cl, Cr);
                    int4 col;
                    col.x = MAX3(A.x, B.x, C.x);
                    col.y = MAX3(A.y, B.y, C.y);
                    col.z = MAX3(A.z, B.z, C.z);
                    col.w = MAX3(A.w, B.w, C.w);
                    int cl = MAX3(Al, Bl, Cl);
                    int cr = MAX3(Ar, Br, Cr);
                    O[j].x = MAX3(cl,    col.x, col.y) | (B.x >> 31);
                    O[j].y = MAX3(col.x, col.y, col.z) | (B.y >> 31);
                    O[j].z = MAX3(col.y, col.z, col.w) | (B.z >> 31);
                    O[j].w = MAX3(col.z, col.w, cr)    | (B.w >> 31);
                    A = B; Al = Bl; Ar = Br;
                    B = C; Bl = Cl; Br = Cr;
                }
            }
            __syncthreads();
            if (active) {
#pragma unroll
                for (int j = 0; j < 8; ++j)
                    *(int4*)&T[(yr + j + 1) * TW + TX0 + x0] = O[j];
            }
            __syncthreads();
        }

        if (r < NROUND - 1) {
            int* dst = (r & 1) ? base1 : base0;
            for (int u = tid; u < 448; u += 256) {
                int lr, lc;
                if (u < 128)      { lr = u >> 4;                lc = u & 15; }
                else if (u < 256) { lr = 56 + ((u - 128) >> 4); lc = u & 15; }
                else { int v = u - 256; lr = 8 + (v >> 2); int s = v & 3; lc = (s < 2) ? s : 12 + s; }
                int4 val = *(const int4*)&T[(HALO + lr + 1) * TW + TX0 + HALO + lc * 4];
                *(int4*)(dst + ((by * CORE + lr) << 9) + bx * CORE + lc * 4) = val;
            }
            __threadfence();
            grid.sync();
            const int* src = (r & 1) ? base1 : base0;
            for (int u = tid; u < 576; u += 256) {
                int lrow, lcu;
                if (u < 160)      { lrow = u / 20;              lcu = u % 20; }
                else if (u < 320) { lrow = 72 + (u - 160) / 20; lcu = u % 20; }
                else { int v = u - 320; lrow = 8 + (v >> 2); int s = v & 3; lcu = (s < 2) ? s : 16 + s; }
                int gy = gy0 + lrow, gx = gx0 + lcu * 4;
                int4 val = (gy >= 0 && gy < 512 && gx >= 0 && gx < 512)
                           ? *(const int4*)(src + (gy << 9) + gx)
                           : make_int4(-1, -1, -1, -1);
                *(int4*)&T[(lrow + 1) * TW + TX0 + lcu * 4] = val;
            }
            __syncthreads();
        } else {
            for (int u = tid; u < 1024; u += 256) {
                int lr = u >> 4, lc = u & 15;
                int4 val = *(const int4*)&T[(HALO + lr + 1) * TW + TX0 + HALO + lc * 4];
                *(int4*)(base0 + ((by * CORE + lr) << 9) + bx * CORE + lc * 4) = val;
            }
        }
    }
#undef LOAD_ROW

    // ---- bits phase: presence bitmap over final labels (in bufA) ----
    __threadfence();
    grid.sync();
    {
        const int* lab = bufA;
        __shared__ unsigned int sk[1024];
        __shared__ int slot[256];
        unsigned int* rep = bm + (blk & (NREP - 1)) * BM_WORDS;
        for (int k = 0; k < 4; ++k) {
            __syncthreads();
            const int i4 = blk * 1024 + k * 256 + tid;
            int4 c = ((const int4*)lab)[i4];
            int pw = __shfl_up(c.w, 1, 64);
            unsigned int prevk;
            if ((tid & 63) == 0) {
                if (i4 == 0) prevk = ~0u;
                else { int pv = lab[i4 * 4 - 1]; prevk = (pv < 0) ? 0u : (unsigned int)pv; }
            } else {
                prevk = (pw < 0) ? 0u : (unsigned int)pw;
            }
            unsigned int k0 = (c.x < 0) ? 0u : (unsigned int)c.x;
            unsigned int k1 = (c.y < 0) ? 0u : (unsigned int)c.y;
            unsigned int k2 = (c.z < 0) ? 0u : (unsigned int)c.z;
            unsigned int k3 = (c.w < 0) ? 0u : (unsigned int)c.w;
            bool c0 = (k0 != prevk), c1 = (k1 != k0), c2 = (k2 != k1), c3 = (k3 != k2);
            sk[0 * 256 + tid] = k0;
            sk[1 * 256 + tid] = k1;
            sk[2 * 256 + tid] = k2;
            sk[3 * 256 + tid] = k3;
            if (c0) slot[k0 & 255] = tid * 4 + 0;
            if (c1) slot[k1 & 255] = tid * 4 + 1;
            if (c2) slot[k2 & 255] = tid * 4 + 2;
            if (c3) slot[k3 & 255] = tid * 4 + 3;
            __syncthreads();
#define SKAT(w) sk[((w) & 3) * 256 + ((w) >> 2)]
            if (c0) { int w = slot[k0 & 255]; if (w != tid * 4 + 0 && SKAT(w) == k0) c0 = false; }
            if (c1) { int w = slot[k1 & 255]; if (w != tid * 4 + 1 && SKAT(w) == k1) c1 = false; }
            if (c2) { int w = slot[k2 & 255]; if (w != tid * 4 + 2 && SKAT(w) == k2) c2 = false; }
            if (c3) { int w = slot[k3 & 255]; if (w != tid * 4 + 3 && SKAT(w) == k3) c3 = false; }
#undef SKAT
#define TSET(kk, cc) if (cc) {                                        \
                unsigned int word = rep[(kk) >> 5];                   \
                if (!((word >> ((kk) & 31)) & 1u))                    \
                    atomicOr(&rep[(kk) >> 5], 1u << ((kk) & 31));     \
            }
            TSET(k0, c0); TSET(k1, c1); TSET(k2, c2); TSET(k3, c3);
#undef TSET
        }
    }

    // ---- popcount phase ----
    __threadfence();
    grid.sync();
    {
        unsigned int c = 0;
        for (int i = blk * 256 + tid; i < BM_WORDS; i += 1024 * 256) {
            unsigned int w = 0;
#pragma unroll
            for (int r = 0; r < NREP; ++r) w |= bm[r * BM_WORDS + i];
            c += __popc(w);
        }
        for (int o = 32; o > 0; o >>= 1)
            c += __shfl_down(c, o, 64);
        __shared__ unsigned int pc[4];
        int lane = tid & 63, w = tid >> 6;
        if (lane == 0) pc[w] = c;
        __syncthreads();
        if (tid == 0 && (pc[0] | pc[1] | pc[2] | pc[3]))
            atomicAdd(nuniq, pc[0] + pc[1] + pc[2] + pc[3]);
    }
}

// ---------- epilogue: reduce slotted accumulators, compose loss ----------
__global__ __launch_bounds__(256) void k_final(const unsigned int* __restrict__ isoArr,
                                               const unsigned int* __restrict__ nuniq,
                                               const float* __restrict__ numArr,
                                               const float* __restrict__ denArr,
                                               float* __restrict__ out) {
    const int tid = threadIdx.x;
    unsigned int isoSum = block_iso(isoArr);

    // per-batch dice: batch b owns slots [64b, 64b+64)
    __shared__ float rn[256], rd[256], lossArr[16];
    int b = tid >> 4, l = tid & 15;
    float sn = 0.f, sd = 0.f;
#pragma unroll
    for (int k = 0; k < 4; ++k) {
        int s = b * 64 + l + 16 * k;
        sn += numArr[s];
        sd += denArr[s];
    }
    rn[tid] = sn; rd[tid] = sd;
    __syncthreads();
    if (l == 0) {
        float tn = 0.f, td = 0.f;
        for (int j = 0; j < 16; ++j) { tn += rn[tid + j]; td += rd[tid + j]; }
        lossArr[b] = 1.0f - (tn + 1.0f) / (td + 1.0f);
    }
    __syncthreads();
    if (tid == 0) {
        float loss = 0.f;
        for (int j = 0; j < 16; ++j) loss += lossArr[j];
        loss *= (1.0f / NB);
        float penalty;
        if (isoSum >= SAT) {
            penalty = (float)NB;               // n_unique >= isoSum >= 256 => clamp == B exactly
        } else {
            penalty = (float)(*nuniq) / (float)NB;
            if (penalty < 1.0f) penalty = (float)NB;
            penalty = fminf(penalty, (float)NB);
        }
        out[0] = loss * penalty;
    }
}

extern "C" void kernel_launch(void* const* d_in, const int* in_sizes, int n_in,
                              void* d_out, int out_size, void* d_ws, size_t ws_size,
                              hipStream_t stream) {
    const float* predict = (const float*)d_in[0];
    const float* target  = (const float*)d_in[1];
    float* out = (float*)d_out;

    // slotted workspace (every consumed slot is written every call — no memset needed):
    //   +0     umaxArr[1024]  +4096 numArr[1024]  +8192 denArr[1024]
    //   +12288 isoArr[512]    +14336 nuniq
    //   +16384 labA (16MB) | labB (16MB) | bm (8MB; fallback-managed)
    char* ws = (char*)d_ws;
    unsigned int* umaxArr = (unsigned int*)ws;
    float* numArr = (float*)(ws + 4096);
    float* denArr = (float*)(ws + 8192);
    unsigned int* isoArr = (unsigned int*)(ws + 12288);
    unsigned int* nuniq  = (unsigned int*)(ws + 14336);
    int* labA = (int*)(ws + 16384);
    int* labB = labA + NPIX;
    unsigned int* bm = (unsigned int*)(ws + 16384 + (size_t)2 * NPIX * sizeof(int));

    k_maxdice<<<1024, 256, 0, stream>>>((const float4*)predict, (const float4*)target,
                                        umaxArr, numArr, denArr);
    k_iso<<<512, 256, 0, stream>>>(predict, umaxArr, isoArr);

    // gated cooperative fallback: propagation + bits + popcount (fast path: immediate exit)
    void* args[] = { (void*)&predict, (void*)&labA, (void*)&labB,
                     (void*)&bm, (void*)&umaxArr, (void*)&isoArr, (void*)&nuniq };
    hipLaunchCooperativeKernel((void*)k_prop_all, dim3(1024), dim3(256), args, 0, stream);

    k_final<<<1, 256, 0, stream>>>(isoArr, nuniq, numArr, denArr, out);
}